// Round 7
// baseline (240.345 us; speedup 1.0000x reference)
//
#include <hip/hip_runtime.h>
#include <math.h>

// Problem geometry (fixed by the reference setup_inputs()).
#define HH 512
#define WW 512
#define BATCH 8
#define PIX (HH * WW)            // 262144 pixels per image
#define NCH 16                   // 8 pred + 8 target channels (fused skeletonize)
#define NPIX_TOT (NCH * PIX)
#define N_ELEM (BATCH * PIX)
#define EPSV 1e-6

// Accumulator layout (doubles at ws[0]):
//  [53..60] cldice sum ps*mask  [61..68] sum ps
//  [69..76] cldice sum ts*p     [77..84] sum ts   (written by engine MODE1)
#define ACC_COUNT 128
#define ACC_BYTES (ACC_COUNT * sizeof(double))
#define NPART 12
#define MRB 2048                 // main-reduce blocks (8/CU -> 32 waves/CU)

__device__ __forceinline__ float sigm(float x) {
    return __fdividef(1.0f, 1.0f + __expf(-x));
}
__device__ __forceinline__ float clamp01(float v) { return fminf(fmaxf(v, 0.0f), 1.0f); }

__device__ __forceinline__ float focal_term(float x, float t, float p) {
    float bce = fmaxf(x, 0.0f) - x * t - __logf(fmaxf(p, 1.0f - p));
    float p_t = p * t + (1.0f - p) * (1.0f - t);
    float a_t = 0.25f * t + 0.75f * (1.0f - t);
    float om  = 1.0f - p_t;
    return a_t * om * om * bce;
}

__device__ __forceinline__ double blockReduceSum(double v, double* sm4) {
    int lane = threadIdx.x & 63, wid = threadIdx.x >> 6;
#pragma unroll
    for (int off = 32; off; off >>= 1) v += __shfl_down(v, off);
    __syncthreads();
    if (lane == 0) sm4[wid] = v;
    __syncthreads();
    double r = 0.0;
    if (threadIdx.x == 0) r = sm4[0] + sm4[1] + sm4[2] + sm4[3];
    return r;
}

// ---------------------------------------------------------------------------
// float4 / 8-wide row helpers
// ---------------------------------------------------------------------------
struct F8 { float4 a, b; };

__device__ __forceinline__ float4 f4min(float4 x, float4 y) {
    return make_float4(fminf(x.x,y.x), fminf(x.y,y.y), fminf(x.z,y.z), fminf(x.w,y.w));
}
__device__ __forceinline__ float4 f4max(float4 x, float4 y) {
    return make_float4(fmaxf(x.x,y.x), fmaxf(x.y,y.y), fmaxf(x.z,y.z), fmaxf(x.w,y.w));
}
__device__ __forceinline__ F8 f8min(F8 x, F8 y) { F8 r; r.a=f4min(x.a,y.a); r.b=f4min(x.b,y.b); return r; }
__device__ __forceinline__ F8 f8max(F8 x, F8 y) { F8 r; r.a=f4max(x.a,y.a); r.b=f4max(x.b,y.b); return r; }
__device__ __forceinline__ F8 f8const(float v) {
    F8 r; r.a = make_float4(v,v,v,v); r.b = r.a; return r;
}
__device__ __forceinline__ F8 f8sigm(F8 x) {
    F8 r;
    r.a = make_float4(sigm(x.a.x), sigm(x.a.y), sigm(x.a.z), sigm(x.a.w));
    r.b = make_float4(sigm(x.b.x), sigm(x.b.y), sigm(x.b.z), sigm(x.b.w));
    return r;
}
__device__ __forceinline__ F8 f8clamp01(F8 x) {
    F8 r;
    r.a = make_float4(clamp01(x.a.x), clamp01(x.a.y), clamp01(x.a.z), clamp01(x.a.w));
    r.b = make_float4(clamp01(x.b.x), clamp01(x.b.y), clamp01(x.b.z), clamp01(x.b.w));
    return r;
}

// soft_erode on one row: min(center, up, down, left, right). Horizontal
// neighbors via in-register shifts + lane-edge shuffles (+inf at x-bounds).
__device__ __forceinline__ F8 erode_row(const F8& up, const F8& ce, const F8& dn, int lane) {
    F8 vm = f8min(f8min(up, dn), ce);
    float Lin = __shfl_up(ce.b.w, 1);
    float Rin = __shfl_down(ce.a.x, 1);
    if (lane == 0)  Lin = INFINITY;
    if (lane == 63) Rin = INFINITY;
    float4 la = make_float4(Lin,    ce.a.x, ce.a.y, ce.a.z);
    float4 lb = make_float4(ce.a.w, ce.b.x, ce.b.y, ce.b.z);
    float4 ra = make_float4(ce.a.y, ce.a.z, ce.a.w, ce.b.x);
    float4 rb = make_float4(ce.b.y, ce.b.z, ce.b.w, Rin);
    F8 r;
    r.a = f4min(vm.a, f4min(la, ra));
    r.b = f4min(vm.b, f4min(lb, rb));
    return r;
}

// 3x3 max of E at one row: separable (vertical max3 then horizontal max3,
// -inf at x-bounds).
__device__ __forceinline__ F8 max3_row(const F8& u, const F8& c, const F8& d, int lane) {
    F8 vm = f8max(f8max(u, d), c);
    float Lin = __shfl_up(vm.b.w, 1);
    float Rin = __shfl_down(vm.a.x, 1);
    if (lane == 0)  Lin = -INFINITY;
    if (lane == 63) Rin = -INFINITY;
    float4 la = make_float4(Lin,    vm.a.x, vm.a.y, vm.a.z);
    float4 lb = make_float4(vm.a.w, vm.b.x, vm.b.y, vm.b.z);
    float4 ra = make_float4(vm.a.y, vm.a.z, vm.a.w, vm.b.x);
    float4 rb = make_float4(vm.b.y, vm.b.z, vm.b.w, Rin);
    F8 r;
    r.a = f4max(vm.a, f4max(la, ra));
    r.b = f4max(vm.b, f4max(lb, rb));
    return r;
}

// t *= (1 - relu(img - mx))   [skel = 1 - t identity for the additive update]
__device__ __forceinline__ float4 f4updt(float4 t, float4 im, float4 mx) {
    return make_float4(t.x * (1.0f - fmaxf(im.x - mx.x, 0.0f)),
                       t.y * (1.0f - fmaxf(im.y - mx.y, 0.0f)),
                       t.z * (1.0f - fmaxf(im.z - mx.z, 0.0f)),
                       t.w * (1.0f - fmaxf(im.w - mx.w, 0.0f)));
}

// ---------------------------------------------------------------------------
// Row-register soft-skeletonize engine (unchanged from round 6).
// Grid: 16 channels x 32 strips = 512 blocks x 256 threads (4 waves).
// Wave w holds rows [S-8+8w, S-8+8w+8); lane covers 8 px as two float4.
// Center waves (1,2) carry the t (transparency) state: skel = 1 - t.
// Halo exchange via DOUBLE-BUFFERED LDS: one barrier per iteration.
// ---------------------------------------------------------------------------
template<int ITERS, int MODE>
__global__ __launch_bounds__(256, 2) void k_skel_engine(
    const float* __restrict__ srcA,   // MODE0: mask_logits ; MODE1: img buffer
    const float* __restrict__ srcB,   // MODE0: mask        ; MODE1: t buffer
    const float* __restrict__ mlg,    // MODE1: mask_logits (cldice, c>=8)
    const float* __restrict__ msk,    // MODE1: mask        (cldice, c<8)
    float* __restrict__ imgOut,       // MODE0
    float* __restrict__ tOut,         // MODE0
    double* __restrict__ acc)         // MODE1
{
    __shared__ float xbuf[2][4][4][WW];  // 64 KB, parity double-buffer
    __shared__ double sm4[4];

    const int tid   = threadIdx.x;
    const int lane  = tid & 63;
    const int w     = tid >> 6;
    const int c     = blockIdx.x >> 5;
    const int strip = blockIdx.x & 31;
    const int S     = strip * 16;
    const int grow0 = S - 8 + w * 8;
    const int x0    = lane * 8;
    const bool hasT = (w == 1 || w == 2);

    F8 img[8], t8[8];

    // ---- load held rows (+inf outside image) ----
#pragma unroll
    for (int j = 0; j < 8; ++j) {
        int g = grow0 + j;
        if (g < 0 || g >= HH) { img[j] = f8const(INFINITY); continue; }
        const float* base;
        if (MODE == 0) base = (c < 8) ? srcA + c * PIX : srcB + (c - 8) * PIX;
        else           base = srcA + c * PIX;
        const float* rp = base + (g << 9) + x0;
        F8 v; v.a = *(const float4*)rp; v.b = *(const float4*)(rp + 4);
        if (MODE == 0) v = (c < 8) ? f8sigm(v) : f8clamp01(v);
        img[j] = v;
    }
    if (MODE == 0) {
#pragma unroll
        for (int j = 0; j < 8; ++j) t8[j] = f8const(1.0f);
    } else {
        if (hasT) {
#pragma unroll
            for (int j = 0; j < 8; ++j) {
                const float* tp = srcB + c * PIX + ((grow0 + j) << 9) + x0;
                t8[j].a = *(const float4*)tp; t8[j].b = *(const float4*)(tp + 4);
            }
        } else {
#pragma unroll
            for (int j = 0; j < 8; ++j) t8[j] = f8const(1.0f);
        }
    }

    // ---- iterations ----
    for (int it = 0; it < ITERS; ++it) {
        const int pb = it & 1;
        *(float4*)&xbuf[pb][w][0][x0]     = img[0].a;
        *(float4*)&xbuf[pb][w][0][x0 + 4] = img[0].b;
        *(float4*)&xbuf[pb][w][1][x0]     = img[1].a;
        *(float4*)&xbuf[pb][w][1][x0 + 4] = img[1].b;
        *(float4*)&xbuf[pb][w][2][x0]     = img[6].a;
        *(float4*)&xbuf[pb][w][2][x0 + 4] = img[6].b;
        *(float4*)&xbuf[pb][w][3][x0]     = img[7].a;
        *(float4*)&xbuf[pb][w][3][x0 + 4] = img[7].b;
        __syncthreads();

        F8 hU0, hU1, hD0, hD1;
        if (w > 0) {
            hU0.a = *(float4*)&xbuf[pb][w-1][2][x0]; hU0.b = *(float4*)&xbuf[pb][w-1][2][x0 + 4];
            hU1.a = *(float4*)&xbuf[pb][w-1][3][x0]; hU1.b = *(float4*)&xbuf[pb][w-1][3][x0 + 4];
        } else { hU0 = f8const(INFINITY); hU1 = f8const(INFINITY); }
        if (w < 3) {
            hD0.a = *(float4*)&xbuf[pb][w+1][0][x0]; hD0.b = *(float4*)&xbuf[pb][w+1][0][x0 + 4];
            hD1.a = *(float4*)&xbuf[pb][w+1][1][x0]; hD1.b = *(float4*)&xbuf[pb][w+1][1][x0 + 4];
        } else { hD0 = f8const(INFINITY); hD1 = f8const(INFINITY); }

        // rolling erode window: Em1 = E[local j-1], E0 = E[j], Ep1 = E[j+1]
        F8 Em1 = erode_row(hU0, hU1, img[0], lane);
        { int g = grow0 - 1; if (g < 0 || g >= HH) Em1 = f8const(-INFINITY); }
        F8 E0  = erode_row(hU1, img[0], img[1], lane);
        { int g = grow0;     if (g < 0 || g >= HH) E0  = f8const(-INFINITY); }

#pragma unroll
        for (int j = 0; j < 8; ++j) {
            F8 ce = (j < 7) ? img[j + 1] : hD0;
            F8 dn = (j < 6) ? img[j + 2] : ((j == 6) ? hD0 : hD1);
            F8 Ep1 = erode_row(img[j], ce, dn, lane);
            { int g = grow0 + j + 1; if (g < 0 || g >= HH) Ep1 = f8const(-INFINITY); }
            if (hasT) {
                F8 mx = max3_row(Em1, E0, Ep1, lane);
                t8[j].a = f4updt(t8[j].a, img[j].a, mx.a);
                t8[j].b = f4updt(t8[j].b, img[j].b, mx.b);
            }
            img[j] = E0;          // img becomes eroded image for next iteration
            Em1 = E0; E0 = Ep1;
        }
    }

    // ---- epilogue ----
    if (MODE == 0) {
        if (hasT) {
#pragma unroll
            for (int j = 0; j < 8; ++j) {
                int g = grow0 + j;
                float* ip = imgOut + c * PIX + (g << 9) + x0;
                *(float4*)ip       = img[j].a;
                *(float4*)(ip + 4) = img[j].b;
                float* tp = tOut + c * PIX + (g << 9) + x0;
                *(float4*)tp       = t8[j].a;
                *(float4*)(tp + 4) = t8[j].b;
            }
        }
    } else {
        double s0 = 0.0, s1 = 0.0;
        if (hasT) {
#pragma unroll
            for (int j = 0; j < 8; ++j) {
                int g = grow0 + j;
                const float* op = (c < 8) ? (msk + c * PIX + (g << 9) + x0)
                                          : (mlg + (c - 8) * PIX + (g << 9) + x0);
                F8 o; o.a = *(const float4*)op; o.b = *(const float4*)(op + 4);
                if (c >= 8) o = f8sigm(o);
                float ps0 = clamp01(1.0f - t8[j].a.x), ps1 = clamp01(1.0f - t8[j].a.y);
                float ps2 = clamp01(1.0f - t8[j].a.z), ps3 = clamp01(1.0f - t8[j].a.w);
                float ps4 = clamp01(1.0f - t8[j].b.x), ps5 = clamp01(1.0f - t8[j].b.y);
                float ps6 = clamp01(1.0f - t8[j].b.z), ps7 = clamp01(1.0f - t8[j].b.w);
                float rs = ((ps0 + ps1) + (ps2 + ps3)) + ((ps4 + ps5) + (ps6 + ps7));
                float rp = ((ps0 * o.a.x + ps1 * o.a.y) + (ps2 * o.a.z + ps3 * o.a.w))
                         + ((ps4 * o.b.x + ps5 * o.b.y) + (ps6 * o.b.z + ps7 * o.b.w));
                s1 += (double)rs;
                s0 += (double)rp;
            }
        }
        __syncthreads();   // re-align waves before reduction LDS use
        double r0 = blockReduceSum(s0, sm4);
        double r1 = blockReduceSum(s1, sm4);
        if (tid == 0) {
            if (c < 8) { atomicAdd(&acc[53 + c], r0);     atomicAdd(&acc[61 + c], r1); }
            else       { atomicAdd(&acc[69 + c - 8], r0); atomicAdd(&acc[77 + c - 8], r1); }
        }
    }
}

// ---------------------------------------------------------------------------
// K1: point-wise losses. 2048 blocks, 4 px/thread (one float4 round, all 14
// loads in flight). Tail: float butterfly per wave (no barriers), lane0 ->
// LDS, ONE barrier, 11 threads write partials. Block 0 also zeros the cldice
// accumulators (replaces the hipMemsetAsync dispatch; engine MODE1's atomics
// run stream-ordered after this kernel).
// ---------------------------------------------------------------------------
__global__ __launch_bounds__(256) void k_main_reduce(
    const float* __restrict__ mask_logits, const float* __restrict__ skel_logits,
    const float* __restrict__ unc_logits,  const float* __restrict__ junc_logits,
    const float* __restrict__ endp_logits, const float* __restrict__ aff_pred,
    const float* __restrict__ mask,        const float* __restrict__ skel,
    const float* __restrict__ junc,        const float* __restrict__ endp,
    const float* __restrict__ aff_tgt,     const float* __restrict__ unc,
    double* __restrict__ part, double* __restrict__ acc)
{
    __shared__ float smq[4][11];
    const int b   = blockIdx.x >> 8;
    const int pix = (blockIdx.x & 255) * 1024 + threadIdx.x * 4;
    const int i   = b * PIX + pix;

    if (blockIdx.x == 0 && threadIdx.x < 32) acc[53 + threadIdx.x] = 0.0;

    float q[11];
#pragma unroll
    for (int t = 0; t < 11; ++t) q[t] = 0.0f;

    float4 ml = *(const float4*)&mask_logits[i];
    float4 mm = *(const float4*)&mask[i];
    float4 sl = *(const float4*)&skel_logits[i];
    float4 ss = *(const float4*)&skel[i];
    float4 jl = *(const float4*)&junc_logits[i];
    float4 jt = *(const float4*)&junc[i];
    float4 el = *(const float4*)&endp_logits[i];
    float4 et = *(const float4*)&endp[i];
    float4 ul = *(const float4*)&unc_logits[i];
    float4 ut = *(const float4*)&unc[i];
    float4 a0 = *(const float4*)&aff_pred[(b * 2 + 0) * PIX + pix];
    float4 t0 = *(const float4*)&aff_tgt [(b * 2 + 0) * PIX + pix];
    float4 a1 = *(const float4*)&aff_pred[(b * 2 + 1) * PIX + pix];
    float4 t1 = *(const float4*)&aff_tgt [(b * 2 + 1) * PIX + pix];

    const float* mlv = (const float*)&ml; const float* mmv = (const float*)&mm;
    const float* slv = (const float*)&sl; const float* ssv = (const float*)&ss;
    const float* jlv = (const float*)&jl; const float* jtv = (const float*)&jt;
    const float* elv = (const float*)&el; const float* etv = (const float*)&et;
    const float* ulv = (const float*)&ul; const float* utv = (const float*)&ut;
    const float* a0v = (const float*)&a0; const float* t0v = (const float*)&t0;
    const float* a1v = (const float*)&a1; const float* t1v = (const float*)&t1;

#pragma unroll
    for (int k = 0; k < 4; ++k) {
        float x = mlv[k], m = mmv[k];
        float p = sigm(x);
        q[0] += p * m; q[1] += p; q[2] += m;
        q[6] += focal_term(x, m, p);

        float sx = slv[k], s = ssv[k];
        float sp = sigm(sx);
        q[3] += sp * s; q[4] += sp; q[5] += s;

        float jx = jlv[k];
        q[7] += focal_term(jx, jtv[k], sigm(jx));
        float ex = elv[k];
        q[8] += focal_term(ex, etv[k], sigm(ex));

        float ud = sigm(ulv[k]) - utv[k];
        q[10] += ud * ud;

        float d0 = a0v[k] * s - t0v[k] * s;
        float ad0 = fabsf(d0);
        q[9] += (ad0 < 1.0f) ? 0.5f * d0 * d0 : ad0 - 0.5f;
        float d1 = a1v[k] * s - t1v[k] * s;
        float ad1 = fabsf(d1);
        q[9] += (ad1 < 1.0f) ? 0.5f * d1 * d1 : ad1 - 0.5f;
    }

    // wave butterfly (float), no barriers
#pragma unroll
    for (int t = 0; t < 11; ++t) {
        float v = q[t];
        v += __shfl_xor(v, 1);  v += __shfl_xor(v, 2);  v += __shfl_xor(v, 4);
        v += __shfl_xor(v, 8);  v += __shfl_xor(v, 16); v += __shfl_xor(v, 32);
        q[t] = v;
    }
    const int lane = threadIdx.x & 63, wid = threadIdx.x >> 6;
    if (lane == 0) {
#pragma unroll
        for (int t = 0; t < 11; ++t) smq[wid][t] = q[t];
    }
    __syncthreads();
    if (threadIdx.x < 11) {
        double v = (double)smq[0][threadIdx.x] + (double)smq[1][threadIdx.x]
                 + (double)smq[2][threadIdx.x] + (double)smq[3][threadIdx.x];
        part[blockIdx.x * NPART + threadIdx.x] = v;
    }
}

// ---------------------------------------------------------------------------
// Combine partials + final scalar loss (one kernel, runs last). MRB = 2048.
// ---------------------------------------------------------------------------
__global__ __launch_bounds__(256) void k_finalize(
    const double* __restrict__ part, const double* __restrict__ acc,
    float* __restrict__ out)
{
    __shared__ double s[53];
    const int wave = threadIdx.x >> 6, lane = threadIdx.x & 63;
    for (int T = wave; T < 53; T += 4) {
        double v = 0.0;
        if (T < 48) {
            int g = T >> 3, bb = T & 7;
            int blk = bb * 256 + lane * 4;
#pragma unroll
            for (int i = 0; i < 4; ++i) v += part[(blk + i) * NPART + g];
        } else {
            int q = 6 + (T - 48);
#pragma unroll
            for (int i = 0; i < 32; ++i) v += part[(lane + 64 * i) * NPART + q];
        }
#pragma unroll
        for (int off = 32; off; off >>= 1) v += __shfl_down(v, off);
        if (lane == 0) s[T] = v;
    }
    __syncthreads();

    if (threadIdx.x != 0) return;
    const double eps = EPSV;
    const double Nd  = (double)N_ELEM;

    double dm = 0, ds = 0, cl = 0, msum = 0;
    for (int b = 0; b < BATCH; ++b) {
        dm += (2.0 * s[0 + b] + eps) / (s[8 + b] + s[16 + b] + eps);
        ds += (2.0 * s[24 + b] + eps) / (s[32 + b] + s[40 + b] + eps);
        double prec = acc[53 + b] / (acc[61 + b] + eps);
        double sens = acc[69 + b] / (acc[77 + b] + eps);
        cl += (2.0 * prec * sens + eps) / (prec + sens + eps);
        msum += s[40 + b];
    }
    msum *= 2.0;   // skeleton mask broadcast over 2 affinity channels

    double mask_loss = (1.0 - dm / 8.0) + s[48] / Nd;
    double skel_loss = 1.0 - ds / 8.0;
    double topo      = 1.0 - cl / 8.0;
    double node      = 0.5 * (s[49] / Nd + s[50] / Nd);
    double aff       = (msum == 0.0) ? 0.0 : s[51] / fmax(msum, 1.0);
    double unc       = s[52] / Nd;

    double total = mask_loss + skel_loss + 0.5 * topo + 0.5 * node + 0.5 * aff + 0.1 * unc;
    out[0] = (float)total;
}

// ---------------------------------------------------------------------------
extern "C" void kernel_launch(void* const* d_in, const int* in_sizes, int n_in,
                              void* d_out, int out_size, void* d_ws, size_t ws_size,
                              hipStream_t stream)
{
    const float* mask_logits = (const float*)d_in[0];
    const float* skel_logits = (const float*)d_in[1];
    const float* unc_logits  = (const float*)d_in[2];
    const float* junc_logits = (const float*)d_in[3];
    const float* endp_logits = (const float*)d_in[4];
    const float* aff_pred    = (const float*)d_in[5];
    const float* mask        = (const float*)d_in[6];
    const float* skel        = (const float*)d_in[7];
    const float* junc        = (const float*)d_in[8];
    const float* endp        = (const float*)d_in[9];
    const float* aff_tgt     = (const float*)d_in[10];
    const float* unc         = (const float*)d_in[11];
    float* out = (float*)d_out;

    char* ws = (char*)d_ws;
    double* acc  = (double*)ws;
    double* part = (double*)(ws + ACC_BYTES);
    float*  P1   = (float*)(ws + ACC_BYTES + MRB * NPART * sizeof(double)); // img_6
    float*  TBUF = P1 + NPIX_TOT;                                           // transparency t
    // ws usage: 1 KiB + 192 KiB + 16 MiB + 16 MiB ~= 33 MiB

    k_main_reduce<<<MRB, 256, 0, stream>>>(
        mask_logits, skel_logits, unc_logits, junc_logits, endp_logits,
        aff_pred, mask, skel, junc, endp, aff_tgt, unc, part, acc);

    // Skeletonize: updates 0..5 then 6..10 (+ fused cldice reduce).
    k_skel_engine<6, 0><<<NCH * 32, 256, 0, stream>>>(
        mask_logits, mask, nullptr, nullptr, P1, TBUF, nullptr);
    k_skel_engine<5, 1><<<NCH * 32, 256, 0, stream>>>(
        P1, TBUF, mask_logits, mask, nullptr, nullptr, acc);

    k_finalize<<<1, 256, 0, stream>>>(part, acc, out);
}